// Round 3
// baseline (244.210 us; speedup 1.0000x reference)
//
#include <hip/hip_runtime.h>

// out[b,h,w,u] = sum_d (w[u,d] - x[b,h,w,d])^2
//              = ||x||^2 - 2 x.w + ||w||^2
// x: [524288, 64] fp32 (134 MB, read once), w: [64, 64] fp32 (16 KB),
// out: [524288, 64] fp32 (134 MB, written once). Memory-bound: ~43 us floor.
//
// Strategy: per-wave 16-row x 64-unit tile via mfma_f32_16x16x32_bf16.
//   A operand = w   (M-dim = units; 8 frags live in registers all kernel)
//   B operand = x   (N-dim = rows; loaded global->reg as 4x dwordx4/lane)
// C/D layout (verified, guide m89): col = lane&15 (row index), row = quad*4+reg
// (unit index) -> each lane holds 4 consecutive units -> dwordx4 stores.
//
// R1 post-mortem: __launch_bounds__(256,8) -> 32-VGPR cap -> scratch spills.
// R2 post-mortem: spill-free 2048-block grid ran EXACTLY like the 1024-block
// grid (82 us, occupancy 29->33%): achieved concurrency is pinned ~10 waves/CU
// regardless of grid. But R1's spill traffic proved the memory system sustains
// >=3.3 TB/s given more outstanding requests. => the kernel is per-wave
// MLP-bound: each iteration is a serial load->wait->compute->store chain.
// R3: (a) depth-2 software pipeline - issue next tile's 4 dwordx4 loads before
// consuming the current tile, hiding HBM latency under cvt/MFMA/store;
// (b) non-temporal output stores so the write-once Out stream doesn't evict
// X from the 256 MB L3 (X is already ~half L3-resident: FETCH 65 of 134 MB).

typedef float  float4v  __attribute__((ext_vector_type(4)));
typedef __bf16 bf16x8   __attribute__((ext_vector_type(8)));

static constexpr int kRows  = 16 * 128 * 256;  // 524288
static constexpr int kTiles = kRows / 16;      // 32768

__device__ __forceinline__ bf16x8 cvt2(float4v a, float4v b) {
  bf16x8 r;
  r[0] = (__bf16)a[0]; r[1] = (__bf16)a[1]; r[2] = (__bf16)a[2]; r[3] = (__bf16)a[3];
  r[4] = (__bf16)b[0]; r[5] = (__bf16)b[1]; r[6] = (__bf16)b[2]; r[7] = (__bf16)b[3];
  return r;
}

__global__ __launch_bounds__(256) void sqdist_kernel(
    const float* __restrict__ X, const float* __restrict__ W,
    float* __restrict__ Out) {
  const int lane = threadIdx.x & 63;
  const int q    = lane >> 4;   // quad 0..3
  const int m    = lane & 15;

  // ---- Setup: w fragments (A operand) + redistributed ||w||^2 ----
  // A layout: A[mdim = lane&15][k = q*8 + j]; frag kf covers k in [32*kf, 32*kf+32).
  bf16x8 aw[4][2];
  float  w2adj[4][4];  // [ut][reg]: ||w_u||^2 for u = 16*ut + q*4 + reg
#pragma unroll
  for (int ut = 0; ut < 4; ++ut) {
    const float4v* wr = (const float4v*)(W + (ut * 16 + m) * 64);
    float4v v0 = wr[q * 2];
    float4v v1 = wr[q * 2 + 1];
    float4v v2 = wr[8 + q * 2];
    float4v v3 = wr[8 + q * 2 + 1];
    aw[ut][0] = cvt2(v0, v1);
    aw[ut][1] = cvt2(v2, v3);
    float s = 0.f;
#pragma unroll
    for (int i = 0; i < 4; ++i)
      s += v0[i] * v0[i] + v1[i] * v1[i] + v2[i] * v2[i] + v3[i] * v3[i];
    s += __shfl_xor(s, 16);      // reduce across quads (lanes m, m+16, m+32, m+48)
    s += __shfl_xor(s, 32);      // -> every lane holds ||w_(16*ut+m)||^2
#pragma unroll
    for (int r = 0; r < 4; ++r)
      w2adj[ut][r] = __shfl(s, q * 4 + r);  // fetch ||w||^2 of the unit this C-reg maps to
  }

  const int gw = blockIdx.x * (blockDim.x >> 6) + (threadIdx.x >> 6);
  const int nw = gridDim.x * (blockDim.x >> 6);

  int tile = gw;
  if (tile >= kTiles) return;

  // ---- Prologue: load tile 0 ----
  // B layout: B[k = q*8 + j][ndim = lane&15]; lane reads row (tile*16+m),
  // floats [q*8 .. q*8+7] and [32+q*8 .. 32+q*8+7]. Every byte read once.
  {
    const float4v* xr = (const float4v*)(X + (tile * 16 + m) * 64);
    // fallthrough into loop with x* live
  }
  const float4v* xr0 = (const float4v*)(X + (tile * 16 + m) * 64);
  float4v x0 = xr0[q * 2];
  float4v x1 = xr0[q * 2 + 1];
  float4v x2 = xr0[8 + q * 2];
  float4v x3 = xr0[8 + q * 2 + 1];

  while (true) {
    // ---- Prefetch next tile BEFORE consuming the current one ----
    const int tnext = tile + nw;          // wave-uniform
    const bool more = tnext < kTiles;
    float4v y0, y1, y2, y3;
    if (more) {
      const float4v* yr = (const float4v*)(X + (tnext * 16 + m) * 64);
      y0 = yr[q * 2];
      y1 = yr[q * 2 + 1];
      y2 = yr[8 + q * 2];
      y3 = yr[8 + q * 2 + 1];
    }

    // ---- ||x_row||^2 in fp32 (partial over this lane's 16 elems, reduce over quads)
    float s = 0.f;
#pragma unroll
    for (int i = 0; i < 4; ++i)
      s += x0[i] * x0[i] + x1[i] * x1[i] + x2[i] * x2[i] + x3[i] * x3[i];
    s += __shfl_xor(s, 16);
    s += __shfl_xor(s, 32);      // s = ||x_(tile*16+m)||^2 ; C-col of this lane is m

    bf16x8 bx0 = cvt2(x0, x1);
    bf16x8 bx1 = cvt2(x2, x3);

    // ---- 8 MFMAs: acc[ut][reg] = dot(w[16*ut + q*4 + reg], x[tile*16 + m]) ----
    float4v acc[4];
#pragma unroll
    for (int ut = 0; ut < 4; ++ut) {
      float4v z = {0.f, 0.f, 0.f, 0.f};
      acc[ut] = __builtin_amdgcn_mfma_f32_16x16x32_bf16(aw[ut][0], bx0, z, 0, 0, 0);
      acc[ut] = __builtin_amdgcn_mfma_f32_16x16x32_bf16(aw[ut][1], bx1, acc[ut], 0, 0, 0);
    }

    // ---- Epilogue: out = x2 + w2 - 2*dot ; 4x dwordx4 coalesced nt stores ----
    float4v* orow = (float4v*)(Out + (tile * 16 + m) * 64);
#pragma unroll
    for (int ut = 0; ut < 4; ++ut) {
      float4v o;
#pragma unroll
      for (int r = 0; r < 4; ++r)
        o[r] = fmaf(-2.f, acc[ut][r], s + w2adj[ut][r]);
      __builtin_nontemporal_store(o, &orow[ut * 4 + q]);  // write-once stream
    }

    if (!more) break;
    tile = tnext;
    x0 = y0; x1 = y1; x2 = y2; x3 = y3;
  }
}

extern "C" void kernel_launch(void* const* d_in, const int* in_sizes, int n_in,
                              void* d_out, int out_size, void* d_ws, size_t ws_size,
                              hipStream_t stream) {
  const float* X = (const float*)d_in[0];
  const float* W = (const float*)d_in[1];
  float* Out = (float*)d_out;
  // 2048 blocks x 4 waves = 8192 waves; 32768 tiles -> exactly 4 tiles/wave:
  // prologue load + 3 pipelined prefetches + final tile computed bare.
  sqdist_kernel<<<2048, 256, 0, stream>>>(X, W, Out);
}

// Round 4
// 239.464 us; speedup vs baseline: 1.0198x; 1.0198x over previous
//
#include <hip/hip_runtime.h>

// out[b,h,w,u] = sum_d (w[u,d] - x[b,h,w,d])^2
//              = ||x||^2 - 2 x.w + ||w||^2
// x: [524288, 64] fp32 (134 MB, read once), w: [64, 64] fp32 (16 KB),
// out: [524288, 64] fp32 (134 MB, written once). Memory-bound: ~32-43 us floor.
//
// Strategy: per-wave 16-row x 64-unit tile via mfma_f32_16x16x32_bf16.
//   A operand = w   (M-dim = units; 8 frags live in registers all kernel)
//   B operand = x   (N-dim = rows; loaded global->reg as 4x dwordx4/lane)
// C/D layout (verified, guide m89): col = lane&15 (row index), row = quad*4+reg.
//
// R1: __launch_bounds__(256,8) -> 32-VGPR cap -> scratch spills. Lesson: but
//     spill traffic PROVED the memory system sustains >=3.3 TB/s w/ more MLP.
// R2: 2048-block spill-free grid == 1024-block grid (82 us): achieved
//     concurrency pins ~10 waves/CU regardless of launched waves.
// R3: depth-2 pipeline raised BW 2.46->2.67 TB/s, but nt stores added +33 MB
//     write amplification (partial-line flushes) and ate the gain.
// R4: the working lever is in-flight bytes PER WAVE. 1024 blocks -> exactly
//     8 tiles/wave; fully-unrolled depth-3 pipeline (loads for k+2 issued
//     before consuming k; 2 tiles = 8 KB outstanding/wave steady-state);
//     plain stores (nt removed). All buffer indices compile-time constants.

typedef float  float4v  __attribute__((ext_vector_type(4)));
typedef __bf16 bf16x8   __attribute__((ext_vector_type(8)));

static constexpr int kRows  = 16 * 128 * 256;   // 524288
static constexpr int kTiles = kRows / 16;       // 32768
static constexpr int kWaves = 1024 * 4;         // grid is fixed at 1024x256
static constexpr int kIters = kTiles / kWaves;  // 8, exact

__device__ __forceinline__ bf16x8 cvt2(float4v a, float4v b) {
  bf16x8 r;
  r[0] = (__bf16)a[0]; r[1] = (__bf16)a[1]; r[2] = (__bf16)a[2]; r[3] = (__bf16)a[3];
  r[4] = (__bf16)b[0]; r[5] = (__bf16)b[1]; r[6] = (__bf16)b[2]; r[7] = (__bf16)b[3];
  return r;
}

__global__ __launch_bounds__(256) void sqdist_kernel(
    const float* __restrict__ X, const float* __restrict__ W,
    float* __restrict__ Out) {
  const int lane = threadIdx.x & 63;
  const int q    = lane >> 4;   // quad 0..3
  const int m    = lane & 15;

  // ---- Setup: w fragments (A operand) + redistributed ||w||^2 ----
  // A layout: A[mdim = lane&15][k = q*8 + j]; frag kf covers k in [32*kf, +32).
  bf16x8 aw[4][2];
  float  w2adj[4][4];  // [ut][reg]: ||w_u||^2 for u = 16*ut + q*4 + reg
#pragma unroll
  for (int ut = 0; ut < 4; ++ut) {
    const float4v* wr = (const float4v*)(W + (ut * 16 + m) * 64);
    float4v v0 = wr[q * 2];
    float4v v1 = wr[q * 2 + 1];
    float4v v2 = wr[8 + q * 2];
    float4v v3 = wr[8 + q * 2 + 1];
    aw[ut][0] = cvt2(v0, v1);
    aw[ut][1] = cvt2(v2, v3);
    float s = 0.f;
#pragma unroll
    for (int i = 0; i < 4; ++i)
      s += v0[i] * v0[i] + v1[i] * v1[i] + v2[i] * v2[i] + v3[i] * v3[i];
    s += __shfl_xor(s, 16);      // reduce across quads
    s += __shfl_xor(s, 32);      // -> every lane holds ||w_(16*ut+m)||^2
#pragma unroll
    for (int r = 0; r < 4; ++r)
      w2adj[ut][r] = __shfl(s, q * 4 + r);
  }

  const int gw = blockIdx.x * 4 + (threadIdx.x >> 6);  // wave id, 0..4095

  // ---- Depth-3 software pipeline over exactly 8 tiles/wave ----
  // B layout per tile: lane reads row (tile*16+m), floats [8q..8q+7] and
  // [32+8q..32+8q+7] as 4x dwordx4. Every byte read exactly once.
  float4v buf[3][4];  // [slot][chunk]; all indices compile-time after unroll

#pragma unroll
  for (int p = 0; p < 2; ++p) {  // prologue: issue loads for tiles 0 and 1
    const int t = gw + p * kWaves;
    const float4v* xr = (const float4v*)(X + (t * 16 + m) * 64);
    buf[p][0] = xr[q * 2];
    buf[p][1] = xr[q * 2 + 1];
    buf[p][2] = xr[8 + q * 2];
    buf[p][3] = xr[8 + q * 2 + 1];
  }

#pragma unroll
  for (int k = 0; k < kIters; ++k) {
    // Prefetch tile k+2 into the slot freed by tile k-1 (same slot index).
    if (k + 2 < kIters) {
      const int t = gw + (k + 2) * kWaves;
      const float4v* xr = (const float4v*)(X + (t * 16 + m) * 64);
      float4v* b = buf[(k + 2) % 3];
      b[0] = xr[q * 2];
      b[1] = xr[q * 2 + 1];
      b[2] = xr[8 + q * 2];
      b[3] = xr[8 + q * 2 + 1];
    }

    const int tile = gw + k * kWaves;
    const float4v x0 = buf[k % 3][0];
    const float4v x1 = buf[k % 3][1];
    const float4v x2 = buf[k % 3][2];
    const float4v x3 = buf[k % 3][3];

    // ||x_row||^2 in fp32 (partial over this lane's 16 elems, reduce over quads)
    float s = 0.f;
#pragma unroll
    for (int i = 0; i < 4; ++i)
      s += x0[i] * x0[i] + x1[i] * x1[i] + x2[i] * x2[i] + x3[i] * x3[i];
    s += __shfl_xor(s, 16);
    s += __shfl_xor(s, 32);      // s = ||x_(tile*16+m)||^2 ; C-col of this lane is m

    bf16x8 bx0 = cvt2(x0, x1);
    bf16x8 bx1 = cvt2(x2, x3);

    // 8 MFMAs: acc[ut][reg] = dot(w[16*ut + q*4 + reg], x[tile*16 + m])
    float4v acc[4];
#pragma unroll
    for (int ut = 0; ut < 4; ++ut) {
      float4v z = {0.f, 0.f, 0.f, 0.f};
      acc[ut] = __builtin_amdgcn_mfma_f32_16x16x32_bf16(aw[ut][0], bx0, z, 0, 0, 0);
      acc[ut] = __builtin_amdgcn_mfma_f32_16x16x32_bf16(aw[ut][1], bx1, acc[ut], 0, 0, 0);
    }

    // Epilogue: out = x2 + w2 - 2*dot ; 4x dwordx4 coalesced stores (plain)
    float4v* orow = (float4v*)(Out + (tile * 16 + m) * 64);
#pragma unroll
    for (int ut = 0; ut < 4; ++ut) {
      float4v o;
#pragma unroll
      for (int r = 0; r < 4; ++r)
        o[r] = fmaf(-2.f, acc[ut][r], s + w2adj[ut][r]);
      orow[ut * 4 + q] = o;   // floats [16*ut + 4*q .. +3] of this row
    }
  }
}

extern "C" void kernel_launch(void* const* d_in, const int* in_sizes, int n_in,
                              void* d_out, int out_size, void* d_ws, size_t ws_size,
                              hipStream_t stream) {
  const float* X = (const float*)d_in[0];
  const float* W = (const float*)d_in[1];
  float* Out = (float*)d_out;
  // 1024 blocks x 4 waves = 4096 waves; 32768 tiles -> exactly 8 tiles/wave,
  // fully unrolled with a depth-3 register pipeline (8 KB in flight/wave).
  sqdist_kernel<<<1024, 256, 0, stream>>>(X, W, Out);
}

// Round 5
// 237.387 us; speedup vs baseline: 1.0287x; 1.0087x over previous
//
#include <hip/hip_runtime.h>

// out[b,h,w,u] = sum_d (w[u,d] - x[b,h,w,d])^2 = ||x||^2 - 2 x.w + ||w||^2
// x: [524288, 64] fp32 (134 MB read once), w: [64,64] fp32 (16 KB),
// out: [524288, 64] fp32 (134 MB written once). Memory-bound, ~43 us floor.
//
// Ladder so far:
// R1: spills proved memory system does >=3.3 TB/s with more outstanding reqs.
// R2: wave count is NOT the lever (2x waves -> +-0; concurrency pins ~10 w/CU).
// R3: +1 in-flight tile/wave -> +9% BW. Per-wave MLP IS the lever.
// R4: compiler sank a register pipeline (VGPR 60 proves it) - source-level
//     reg pipelining gets undone (guide m131-m141).
// R5: async global_load_lds staging into 4 per-wave LDS slots + hand-counted
//     s_waitcnt vmcnt(N). DMA is fire-and-forget (no dest VGPRs to reschedule)
//     and each staging inst copies a CONTIGUOUS 1KB (16 fully-used lines vs 32
//     half-used before -> halves read line-transactions). No __syncthreads
//     anywhere: waves own their slots, so no barrier-drain problem.
//     LDS layout XOR-swizzled (granule j ^= row&7) so ds_read_b128 fragment
//     reads spread uniformly over banks; the swizzle is applied on the GLOBAL
//     source address (rule #21: gload_lds dest must stay linear) and stays
//     within each 256B row -> coalescing preserved.
//     vmcnt counts: N = number of YOUNGER LOADS only (stores in the queue can
//     only make the wait stricter, never unsafe, regardless of store
//     retirement order).

typedef float  float4v  __attribute__((ext_vector_type(4)));
typedef __bf16 bf16x8   __attribute__((ext_vector_type(8)));

static constexpr int kRows  = 16 * 128 * 256;   // 524288
static constexpr int kTiles = kRows / 16;       // 32768
static constexpr int kWaves = 1024 * 4;         // grid fixed: 1024 blocks x 4 waves
static constexpr int kIters = kTiles / kWaves;  // 8, exact
static constexpr int kSlots = 4;                // pipeline depth (LDS slots/wave)

typedef const __attribute__((address_space(1))) void gas_t;  // global
typedef __attribute__((address_space(3))) void las_t;        // LDS

__device__ __forceinline__ bf16x8 cvt2(float4v a, float4v b) {
  bf16x8 r;
  r[0] = (__bf16)a[0]; r[1] = (__bf16)a[1]; r[2] = (__bf16)a[2]; r[3] = (__bf16)a[3];
  r[4] = (__bf16)b[0]; r[5] = (__bf16)b[1]; r[6] = (__bf16)b[2]; r[7] = (__bf16)b[3];
  return r;
}

__global__ __launch_bounds__(256) void sqdist_kernel(
    const float* __restrict__ X, const float* __restrict__ W,
    float* __restrict__ Out) {
  // 4 waves x 4 slots x 256 granules(16B) = 64 KB -> 2 blocks/CU resident.
  __shared__ float4v lds[4][kSlots][256];

  const int lane = threadIdx.x & 63;
  const int wid  = threadIdx.x >> 6;
  const int q    = lane >> 4;   // quad 0..3
  const int m    = lane & 15;

  // ---- Setup: w fragments (A operand) + redistributed ||w||^2 ----
  bf16x8 aw[4][2];
  float  w2adj[4][4];  // [ut][reg]: ||w_u||^2 for u = 16*ut + q*4 + reg
#pragma unroll
  for (int ut = 0; ut < 4; ++ut) {
    const float4v* wr = (const float4v*)(W + (ut * 16 + m) * 64);
    float4v v0 = wr[q * 2];
    float4v v1 = wr[q * 2 + 1];
    float4v v2 = wr[8 + q * 2];
    float4v v3 = wr[8 + q * 2 + 1];
    aw[ut][0] = cvt2(v0, v1);
    aw[ut][1] = cvt2(v2, v3);
    float s = 0.f;
#pragma unroll
    for (int i = 0; i < 4; ++i)
      s += v0[i] * v0[i] + v1[i] * v1[i] + v2[i] * v2[i] + v3[i] * v3[i];
    s += __shfl_xor(s, 16);
    s += __shfl_xor(s, 32);
#pragma unroll
    for (int r = 0; r < 4; ++r)
      w2adj[ut][r] = __shfl(s, q * 4 + r);
  }

  const int gw = blockIdx.x * 4 + wid;  // wave id 0..4095; 8 tiles/wave

  // ---- Staging source offsets (floats within a 1024-float tile) ----
  // Staging inst c, lane l writes LDS granule G = c*64 + l  (HW: base+lane*16),
  // i.e. physical (row r = c*4+q, granule j = m). Physical (r,j) must hold
  // logical granule (r, j ^ (r&7))  -> src float offset below. The XOR stays
  // within the row's 256B -> each inst still covers contiguous full lines.
  int soff[4];
#pragma unroll
  for (int c = 0; c < 4; ++c) {
    const int r = c * 4 + q;
    soff[c] = r * 64 + ((m ^ (r & 7)) << 2);
  }

  // ---- Prologue: stage tiles 0..3 into slots 0..3 (16 DMA loads) ----
#pragma unroll
  for (int p = 0; p < kSlots; ++p) {
    const float* src = X + (size_t)(gw + p * kWaves) * 1024;
#pragma unroll
    for (int c = 0; c < 4; ++c) {
      __builtin_amdgcn_global_load_lds((gas_t*)(src + soff[c]),
                                       (las_t*)&lds[wid][p][c * 64], 16, 0, 0);
    }
  }

  // Fragment read granules: lane (q,m) needs logical granules {2q, 2q+1,
  // 8+2q, 8+2q+1} of row m -> physical index ^ (m&7) (bit3 untouched).
  const int gA = (2 * q)     ^ (m & 7);
  const int gB = (2 * q + 1) ^ (m & 7);

#pragma unroll
  for (int k = 0; k < kIters; ++k) {
    // Wait for tile k's DMA. N = count of younger LOADS in the vmcnt queue
    // (loads retire in order among themselves; interleaved stores only make
    // the wait stricter). Schedule: k<=4 -> 12, then 8, 4, 0.
    if (k <= 4)      asm volatile("s_waitcnt vmcnt(12)" ::: "memory");
    else if (k == 5) asm volatile("s_waitcnt vmcnt(8)"  ::: "memory");
    else if (k == 6) asm volatile("s_waitcnt vmcnt(4)"  ::: "memory");
    else             asm volatile("s_waitcnt vmcnt(0)"  ::: "memory");
    __builtin_amdgcn_sched_barrier(0);

    const float4v* slot = lds[wid][k & (kSlots - 1)];
    const float4v x0 = slot[m * 16 + gA];        // floats 8q..8q+3   of row m
    const float4v x1 = slot[m * 16 + gB];        // floats 8q+4..8q+7
    const float4v x2 = slot[m * 16 + 8 + gA];    // floats 32+8q..
    const float4v x3 = slot[m * 16 + 8 + gB];    // floats 36+8q..

    // ||x_row||^2 in fp32 (partial over this lane's 16 elems, reduce quads)
    float s = 0.f;
#pragma unroll
    for (int i = 0; i < 4; ++i)
      s += x0[i] * x0[i] + x1[i] * x1[i] + x2[i] * x2[i] + x3[i] * x3[i];
    s += __shfl_xor(s, 16);
    s += __shfl_xor(s, 32);      // s = ||x_(tile*16+m)||^2 (C-col of lane = m)

    bf16x8 bx0 = cvt2(x0, x1);
    bf16x8 bx1 = cvt2(x2, x3);

    // All LDS reads (ds_read + shuffle bpermutes) retired -> slot reusable.
    asm volatile("s_waitcnt lgkmcnt(0)" ::: "memory");
    __builtin_amdgcn_sched_barrier(0);

    // Re-stage this slot with tile k+4 (issued early, ahead of MFMA+stores).
    if (k + kSlots < kIters) {
      const float* src = X + (size_t)(gw + (k + kSlots) * kWaves) * 1024;
#pragma unroll
      for (int c = 0; c < 4; ++c) {
        __builtin_amdgcn_global_load_lds(
            (gas_t*)(src + soff[c]),
            (las_t*)&lds[wid][k & (kSlots - 1)][c * 64], 16, 0, 0);
      }
    }

    // 8 MFMAs: acc[ut][reg] = dot(w[16*ut + q*4 + reg], x[tile*16 + m])
    float4v acc[4];
#pragma unroll
    for (int ut = 0; ut < 4; ++ut) {
      float4v z = {0.f, 0.f, 0.f, 0.f};
      acc[ut] = __builtin_amdgcn_mfma_f32_16x16x32_bf16(aw[ut][0], bx0, z, 0, 0, 0);
      acc[ut] = __builtin_amdgcn_mfma_f32_16x16x32_bf16(aw[ut][1], bx1, acc[ut], 0, 0, 0);
    }

    // Epilogue: out = x2 + w2 - 2*dot ; 4x dwordx4 coalesced stores (plain)
    const int tile = gw + k * kWaves;
    float4v* orow = (float4v*)(Out + (size_t)(tile * 16 + m) * 64);
#pragma unroll
    for (int ut = 0; ut < 4; ++ut) {
      float4v o;
#pragma unroll
      for (int r = 0; r < 4; ++r)
        o[r] = fmaf(-2.f, acc[ut][r], s + w2adj[ut][r]);
      orow[ut * 4 + q] = o;
    }
  }
}

extern "C" void kernel_launch(void* const* d_in, const int* in_sizes, int n_in,
                              void* d_out, int out_size, void* d_ws, size_t ws_size,
                              hipStream_t stream) {
  const float* X = (const float*)d_in[0];
  const float* W = (const float*)d_in[1];
  float* Out = (float*)d_out;
  // 1024 blocks x 256 (4 waves): 8 tiles/wave exact; 64KB LDS -> 2 blocks/CU
  // resident, 16 KB of reads in flight per wave via 4-slot async DMA pipeline.
  sqdist_kernel<<<1024, 256, 0, stream>>>(X, W, Out);
}

// Round 6
// 234.091 us; speedup vs baseline: 1.0432x; 1.0141x over previous
//
#include <hip/hip_runtime.h>

// out[b,h,w,u] = sum_d (w[u,d] - x[b,h,w,d])^2 = ||x||^2 - 2 x.w + ||w||^2
// x: [524288, 64] fp32 (134 MB read once), w: [64,64] fp32 (16 KB),
// out: [524288, 64] fp32 (134 MB written once). Memory-bound, ~43 us floor.
//
// Ladder:
// R1: spills proved memory moves >=3.3 TB/s given more requests.
// R2: wave count not the lever (2x waves -> +-0).
// R3: +1 in-flight tile -> +9%; nt on HALF-LINE stores amplified writes +33MB.
// R4: compiler sinks register pipelines (VGPR 60).
// R5: real 4-deep LDS-DMA pipeline, counted vmcnt, swizzled reads -> STILL 82us.
//     => per-wave MLP exhausted; marginal-rate fit across rounds shows extra
//     bytes flow at ~5.2 TB/s. The invariant through all rounds: the STORE
//     path. Stores are 64B half-line chunks that ALLOCATE in L2/L3 -> the
//     134MB Out stream evicts X from L3 every dispatch (FETCH=65MB of a
//     134MB, L3-fitting input).
// R6: full-line non-temporal stores. Epilogue bounces the 16x64 acc tile
//     through the consumed LDS slot to transpose lane ownership into
//     line-contiguous layout: each store inst = contiguous 1KB = 8 FULL
//     128B lines, nt -> no partial-line amplification (R3's failure), Out
//     stops evicting X from L3 -> read stream served from L3, HBM mostly
//     writes. Slot restage moves after the epilogue reads; vmcnt table
//     recomputed for the new issue order.

typedef float  float4v  __attribute__((ext_vector_type(4)));
typedef __bf16 bf16x8   __attribute__((ext_vector_type(8)));

static constexpr int kRows  = 16 * 128 * 256;   // 524288
static constexpr int kTiles = kRows / 16;       // 32768
static constexpr int kWaves = 1024 * 4;         // grid fixed: 1024 blocks x 4 waves
static constexpr int kIters = kTiles / kWaves;  // 8, exact
static constexpr int kSlots = 4;                // pipeline depth (LDS slots/wave)

typedef const __attribute__((address_space(1))) void gas_t;  // global
typedef __attribute__((address_space(3))) void las_t;        // LDS

__device__ __forceinline__ bf16x8 cvt2(float4v a, float4v b) {
  bf16x8 r;
  r[0] = (__bf16)a[0]; r[1] = (__bf16)a[1]; r[2] = (__bf16)a[2]; r[3] = (__bf16)a[3];
  r[4] = (__bf16)b[0]; r[5] = (__bf16)b[1]; r[6] = (__bf16)b[2]; r[7] = (__bf16)b[3];
  return r;
}

__global__ __launch_bounds__(256) void sqdist_kernel(
    const float* __restrict__ X, const float* __restrict__ W,
    float* __restrict__ Out) {
  // 4 waves x 4 slots x 256 granules(16B) = 64 KB -> 2 blocks/CU resident.
  __shared__ float4v lds[4][kSlots][256];

  const int lane = threadIdx.x & 63;
  const int wid  = threadIdx.x >> 6;
  const int q    = lane >> 4;   // quad 0..3
  const int m    = lane & 15;

  // ---- Setup: w fragments (A operand) + redistributed ||w||^2 ----
  bf16x8 aw[4][2];
  float  w2adj[4][4];  // [ut][reg]: ||w_u||^2 for u = 16*ut + q*4 + reg
#pragma unroll
  for (int ut = 0; ut < 4; ++ut) {
    const float4v* wr = (const float4v*)(W + (ut * 16 + m) * 64);
    float4v v0 = wr[q * 2];
    float4v v1 = wr[q * 2 + 1];
    float4v v2 = wr[8 + q * 2];
    float4v v3 = wr[8 + q * 2 + 1];
    aw[ut][0] = cvt2(v0, v1);
    aw[ut][1] = cvt2(v2, v3);
    float s = 0.f;
#pragma unroll
    for (int i = 0; i < 4; ++i)
      s += v0[i] * v0[i] + v1[i] * v1[i] + v2[i] * v2[i] + v3[i] * v3[i];
    s += __shfl_xor(s, 16);
    s += __shfl_xor(s, 32);
#pragma unroll
    for (int r = 0; r < 4; ++r)
      w2adj[ut][r] = __shfl(s, q * 4 + r);
  }

  const int gw = blockIdx.x * 4 + wid;  // wave id 0..4095; 8 tiles/wave

  // ---- Staging source offsets (floats within a 1024-float tile) ----
  // Staging inst c, lane l writes LDS granule c*64+l = physical (row r=c*4+q,
  // granule j=m). Physical (r,j) holds logical granule (r, j^(r&7)) -> XOR on
  // the GLOBAL source (rule #21), stays within the 256B row -> coalescing kept.
  int soff[4];
#pragma unroll
  for (int c = 0; c < 4; ++c) {
    const int r = c * 4 + q;
    soff[c] = r * 64 + ((m ^ (r & 7)) << 2);
  }

  // ---- Prologue: stage tiles 0..3 into slots 0..3 (16 DMA loads) ----
#pragma unroll
  for (int p = 0; p < kSlots; ++p) {
    const float* src = X + (size_t)(gw + p * kWaves) * 1024;
#pragma unroll
    for (int c = 0; c < 4; ++c) {
      __builtin_amdgcn_global_load_lds((gas_t*)(src + soff[c]),
                                       (las_t*)&lds[wid][p][c * 64], 16, 0, 0);
    }
  }

  // Fragment read granules: lane (q,m) needs logical granules {2q,2q+1,
  // 8+2q,8+2q+1} of row m -> physical ^ (m&7) (bit3 untouched).
  const int gA = (2 * q)     ^ (m & 7);
  const int gB = (2 * q + 1) ^ (m & 7);

#pragma unroll
  for (int k = 0; k < kIters; ++k) {
    // Wait for tile k's 4 DMA loads. Issue order (steady state):
    // L0,L1,L2,L3 | S0,L4 | S1,L5 | S2,L6 | S3,L7 | S4 | ... (4 ops each).
    // N = count of entries younger than L(k): {12,16,20,24,24,20,16,12}.
    // vmcnt decrements in issue order, so <=N outstanding => L(k) retired.
    if (k == 0)                asm volatile("s_waitcnt vmcnt(12)" ::: "memory");
    else if (k == 1)           asm volatile("s_waitcnt vmcnt(16)" ::: "memory");
    else if (k == 2)           asm volatile("s_waitcnt vmcnt(20)" ::: "memory");
    else if (k == 3 || k == 4) asm volatile("s_waitcnt vmcnt(24)" ::: "memory");
    else if (k == 5)           asm volatile("s_waitcnt vmcnt(20)" ::: "memory");
    else if (k == 6)           asm volatile("s_waitcnt vmcnt(16)" ::: "memory");
    else                       asm volatile("s_waitcnt vmcnt(12)" ::: "memory");
    __builtin_amdgcn_sched_barrier(0);

    float4v* slot = lds[wid][k & (kSlots - 1)];
    const float4v x0 = slot[m * 16 + gA];        // floats 8q..8q+3   of row m
    const float4v x1 = slot[m * 16 + gB];        // floats 8q+4..8q+7
    const float4v x2 = slot[m * 16 + 8 + gA];    // floats 32+8q..
    const float4v x3 = slot[m * 16 + 8 + gB];    // floats 36+8q..

    // ||x_row||^2 in fp32 (partial over this lane's 16 elems, reduce quads)
    float s = 0.f;
#pragma unroll
    for (int i = 0; i < 4; ++i)
      s += x0[i] * x0[i] + x1[i] * x1[i] + x2[i] * x2[i] + x3[i] * x3[i];
    s += __shfl_xor(s, 16);
    s += __shfl_xor(s, 32);      // s = ||x_(tile*16+m)||^2 (C-col of lane = m)

    bf16x8 bx0 = cvt2(x0, x1);
    bf16x8 bx1 = cvt2(x2, x3);

    // 8 MFMAs: acc[ut][reg] = dot(w[16*ut + q*4 + reg], x[tile*16 + m])
    float4v acc[4];
#pragma unroll
    for (int ut = 0; ut < 4; ++ut) {
      float4v z = {0.f, 0.f, 0.f, 0.f};
      acc[ut] = __builtin_amdgcn_mfma_f32_16x16x32_bf16(aw[ut][0], bx0, z, 0, 0, 0);
      acc[ut] = __builtin_amdgcn_mfma_f32_16x16x32_bf16(aw[ut][1], bx1, acc[ut], 0, 0, 0);
    }

    // ---- Epilogue: transpose lane ownership through the consumed slot so
    // every store instruction writes a CONTIGUOUS 1KB (8 full 128B lines),
    // then non-temporal store (Out must not allocate in L3 and evict X).
    // Write: o[ut] = out[row m][cols 16ut+4q..+3] -> slot granule m*16+4ut+q.
    // (slot x-data already consumed; DS pipe is in-order + values data-depend
    // on the x reads, so no extra fence needed before the overwrite.)
#pragma unroll
    for (int ut = 0; ut < 4; ++ut) {
      float4v o;
#pragma unroll
      for (int r = 0; r < 4; ++r)
        o[r] = fmaf(-2.f, acc[ut][r], s + w2adj[ut][r]);
      slot[m * 16 + 4 * ut + q] = o;
    }

    // Read back line-contiguous: inst j, lane l -> rows 4j+(l>>4), 16B chunk
    // (l&15) -> granule (4j + (l>>4))*16 + (l&15); nt-store 1KB contiguous.
    const int hi = lane >> 4;   // == q
    const int lo = lane & 15;   // == m
    float4v* otile = (float4v*)(Out + (size_t)(gw + (size_t)k * kWaves) * 1024);
#pragma unroll
    for (int j = 0; j < 4; ++j) {
      const int gidx = (4 * j + hi) * 16 + lo;
      float4v o = slot[gidx];
      __builtin_nontemporal_store(o, &otile[gidx]);
    }

    // ---- Re-stage this slot with tile k+4 (after epilogue reads retired;
    // the nt-store address reuse of gidx keeps data deps; fence for safety).
    if (k + kSlots < kIters) {
      asm volatile("s_waitcnt lgkmcnt(0)" ::: "memory");
      __builtin_amdgcn_sched_barrier(0);
      const float* src = X + (size_t)(gw + (k + kSlots) * kWaves) * 1024;
#pragma unroll
      for (int c = 0; c < 4; ++c) {
        __builtin_amdgcn_global_load_lds(
            (gas_t*)(src + soff[c]),
            (las_t*)&lds[wid][k & (kSlots - 1)][c * 64], 16, 0, 0);
      }
    }
  }
}

extern "C" void kernel_launch(void* const* d_in, const int* in_sizes, int n_in,
                              void* d_out, int out_size, void* d_ws, size_t ws_size,
                              hipStream_t stream) {
  const float* X = (const float*)d_in[0];
  const float* W = (const float*)d_in[1];
  float* Out = (float*)d_out;
  // 1024 blocks x 256 (4 waves): 8 tiles/wave exact; 64KB LDS -> 2 blocks/CU.
  // 4-slot DMA read pipeline + full-line nt store epilogue via LDS bounce.
  sqdist_kernel<<<1024, 256, 0, stream>>>(X, W, Out);
}